// Round 2
// baseline (6805.419 us; speedup 1.0000x reference)
//
#include <hip/hip_runtime.h>
#include <math.h>

#define DEV __device__ __forceinline__
DEV float frelu(float x) { return x > 0.f ? x : 0.f; }

// ---------------------------------------------------------------------------
// Stage 1: x(B,50,500,3) -> conv3->32 relu -> conv32->32 relu ; e1 = tanh(att)
// pooled max over 5 -> x1p(B,50,100,32). Thread = one pool group (5 pixels).
// Weights read via wave-uniform indices -> scalar loads; activations in regs.
// ---------------------------------------------------------------------------
__global__ __launch_bounds__(256) void k_s1(
    const float* __restrict__ x,
    const float* __restrict__ w1, const float* __restrict__ b1,
    const float* __restrict__ w2, const float* __restrict__ b2,
    const float* __restrict__ aW, const float* __restrict__ ab,
    float* __restrict__ x1p, float* __restrict__ e1)
{
    int T = blockIdx.x * 256 + threadIdx.x;          // 320000 pool groups
    int b = T / 5000; int r = T % 5000; int h = r / 100; int pw = r % 100;
    const float* xrow = x + (size_t)((b * 50 + h) * 500) * 3;

    float vmax[32];
#pragma unroll
    for (int o = 0; o < 32; ++o) vmax[o] = 0.f;

#pragma unroll 1
    for (int j = 0; j < 5; ++j) {
        int w = pw * 5 + j;
        float x0 = xrow[w * 3 + 0], x1 = xrow[w * 3 + 1], x2 = xrow[w * 3 + 2];
        float v1[32];
#pragma unroll
        for (int o = 0; o < 32; ++o)
            v1[o] = frelu(fmaf(x0, w1[o], fmaf(x1, w1[32 + o], fmaf(x2, w1[64 + o], b1[o]))));
        float v2[32];
#pragma unroll
        for (int o = 0; o < 32; ++o) v2[o] = b2[o];
#pragma unroll
        for (int i = 0; i < 32; ++i) {
            float a = v1[i];
#pragma unroll
            for (int o = 0; o < 32; ++o) v2[o] = fmaf(a, w2[i * 32 + o], v2[o]);
        }
        float e = ab[h * 500 + w];
#pragma unroll
        for (int o = 0; o < 32; ++o) {
            float t = frelu(v2[o]);
            vmax[o] = fmaxf(vmax[o], t);
            e = fmaf(t, aW[h * 32 + o], e);
        }
        e1[(b * 50 + h) * 500 + w] = tanhf(e);
    }
    float* dst = x1p + (size_t)((b * 50 + h) * 100 + pw) * 32;
#pragma unroll
    for (int o = 0; o < 32; ++o) dst[o] = vmax[o];
}

// ---------------------------------------------------------------------------
// Stage 2: x1p -> conv32->64 relu -> conv64->64 relu ; e2 ; pool5 -> x2p
// Thread = (pool group, 16-channel slice q in 0..3). v1 shared via LDS.
// ---------------------------------------------------------------------------
__global__ __launch_bounds__(256) void k_s2(
    const float* __restrict__ x1p,
    const float* __restrict__ w1, const float* __restrict__ b1,
    const float* __restrict__ w2, const float* __restrict__ b2,
    const float* __restrict__ aW, const float* __restrict__ ab,
    float* __restrict__ x2p, float* __restrict__ e2)
{
    __shared__ float v1buf[64][66];
    int tid = threadIdx.x;
    int T = blockIdx.x * 256 + tid;
    int q = T & 3; int G = T >> 2;                   // 256000 threads, 64000 groups
    int b = G / 1000; int rr = G % 1000; int h = rr / 20; int pw = rr % 20;
    int gl = tid >> 2;

    float vmax[16];
#pragma unroll
    for (int o = 0; o < 16; ++o) vmax[o] = 0.f;

#pragma unroll 1
    for (int j = 0; j < 5; ++j) {
        int w = pw * 5 + j;
        const float* in = x1p + (size_t)((b * 50 + h) * 100 + w) * 32;
        float v1[16];
#pragma unroll
        for (int o = 0; o < 16; ++o) v1[o] = b1[q * 16 + o];
#pragma unroll
        for (int i = 0; i < 32; ++i) {
            float a = in[i];
#pragma unroll
            for (int o = 0; o < 16; ++o) v1[o] = fmaf(a, w1[i * 64 + q * 16 + o], v1[o]);
        }
#pragma unroll
        for (int o = 0; o < 16; ++o) v1buf[gl][q * 16 + o] = frelu(v1[o]);
        __syncthreads();
        float v2[16];
#pragma unroll
        for (int o = 0; o < 16; ++o) v2[o] = b2[q * 16 + o];
#pragma unroll
        for (int i = 0; i < 64; ++i) {
            float a = v1buf[gl][i];
#pragma unroll
            for (int o = 0; o < 16; ++o) v2[o] = fmaf(a, w2[i * 64 + q * 16 + o], v2[o]);
        }
        float ep = 0.f;
#pragma unroll
        for (int o = 0; o < 16; ++o) {
            float t = frelu(v2[o]);
            vmax[o] = fmaxf(vmax[o], t);
            ep = fmaf(t, aW[h * 64 + q * 16 + o], ep);
        }
        ep += __shfl_xor(ep, 1, 64);
        ep += __shfl_xor(ep, 2, 64);
        if (q == 0) e2[(b * 50 + h) * 100 + w] = tanhf(ep + ab[h * 100 + w]);
        __syncthreads();
    }
    float* dst = x2p + (size_t)((b * 50 + h) * 20 + pw) * 64 + q * 16;
#pragma unroll
    for (int o = 0; o < 16; ++o) dst[o] = vmax[o];
}

// ---------------------------------------------------------------------------
// Stage 3: x2p -> conv64->128 relu -> conv128->128 relu ; e3 ; pool4 -> x3p
// Thread = (pool group, 16-channel slice q in 0..7).
// ---------------------------------------------------------------------------
__global__ __launch_bounds__(256) void k_s3(
    const float* __restrict__ x2p,
    const float* __restrict__ w1, const float* __restrict__ b1,
    const float* __restrict__ w2, const float* __restrict__ b2,
    const float* __restrict__ aW, const float* __restrict__ ab,
    float* __restrict__ x3p, float* __restrict__ e3)
{
    __shared__ float v1buf[32][130];
    int tid = threadIdx.x;
    int T = blockIdx.x * 256 + tid;
    int q = T & 7; int G = T >> 3;                   // 128000 threads, 16000 groups
    int b = G / 250; int rr = G % 250; int h = rr / 5; int pw = rr % 5;
    int gl = tid >> 3;

    float vmax[16];
#pragma unroll
    for (int o = 0; o < 16; ++o) vmax[o] = 0.f;

#pragma unroll 1
    for (int j = 0; j < 4; ++j) {
        int w = pw * 4 + j;
        const float* in = x2p + (size_t)((b * 50 + h) * 20 + w) * 64;
        float v1[16];
#pragma unroll
        for (int o = 0; o < 16; ++o) v1[o] = b1[q * 16 + o];
#pragma unroll
        for (int i = 0; i < 64; ++i) {
            float a = in[i];
#pragma unroll
            for (int o = 0; o < 16; ++o) v1[o] = fmaf(a, w1[i * 128 + q * 16 + o], v1[o]);
        }
#pragma unroll
        for (int o = 0; o < 16; ++o) v1buf[gl][q * 16 + o] = frelu(v1[o]);
        __syncthreads();
        float v2[16];
#pragma unroll
        for (int o = 0; o < 16; ++o) v2[o] = b2[q * 16 + o];
#pragma unroll
        for (int i = 0; i < 128; ++i) {
            float a = v1buf[gl][i];
#pragma unroll
            for (int o = 0; o < 16; ++o) v2[o] = fmaf(a, w2[i * 128 + q * 16 + o], v2[o]);
        }
        float ep = 0.f;
#pragma unroll
        for (int o = 0; o < 16; ++o) {
            float t = frelu(v2[o]);
            vmax[o] = fmaxf(vmax[o], t);
            ep = fmaf(t, aW[h * 128 + q * 16 + o], ep);
        }
        ep += __shfl_xor(ep, 1, 64);
        ep += __shfl_xor(ep, 2, 64);
        ep += __shfl_xor(ep, 4, 64);
        if (q == 0) e3[(b * 50 + h) * 20 + w] = tanhf(ep + ab[h * 20 + w]);
        __syncthreads();
    }
    float* dst = x3p + (size_t)((b * 50 + h) * 5 + pw) * 128 + q * 16;
#pragma unroll
    for (int o = 0; o < 16; ++o) dst[o] = vmax[o];
}

// ---------------------------------------------------------------------------
// Top-k (k=10, jax.lax.top_k semantics: sorted desc, ties -> lower index)
// + gather: recompute conv features at the selected pixels, write into z.
// One wave per (b,h) row.
// ---------------------------------------------------------------------------
__global__ __launch_bounds__(64) void k_t1(
    const float* __restrict__ e1, const float* __restrict__ x,
    const float* __restrict__ w1, const float* __restrict__ b1,
    const float* __restrict__ w2, const float* __restrict__ b2,
    float* __restrict__ z)
{
    int blk = blockIdx.x; int b = blk / 50; int h = blk % 50;
    int lane = threadIdx.x;
    const float* er = e1 + (b * 50 + h) * 500;
    float ev[8];
#pragma unroll
    for (int s = 0; s < 8; ++s) { int w = lane + s * 64; ev[s] = (w < 500) ? er[w] : -1e30f; }

    for (int k = 0; k < 10; ++k) {
        float bv = -1e30f; int bi = 0;
#pragma unroll
        for (int s = 0; s < 8; ++s) {
            int w = lane + s * 64;
            if (ev[s] > bv) { bv = ev[s]; bi = w; }
        }
#pragma unroll
        for (int d = 1; d < 64; d <<= 1) {
            float ov = __shfl_xor(bv, d, 64); int oi = __shfl_xor(bi, d, 64);
            if (ov > bv || (ov == bv && oi < bi)) { bv = ov; bi = oi; }
        }
        if ((bi & 63) == lane) ev[bi >> 6] = -1e30f;
        // gather: recompute x1 features at pixel bi
        const float* px = x + (size_t)((b * 50 + h) * 500 + bi) * 3;
        float x0 = px[0], x1 = px[1], x2 = px[2];
        int o = lane & 31;
        float v1 = frelu(fmaf(x0, w1[o], fmaf(x1, w1[32 + o], fmaf(x2, w1[64 + o], b1[o]))));
        float v2 = b2[o];
#pragma unroll
        for (int i = 0; i < 32; ++i) v2 = fmaf(__shfl(v1, i, 64), w2[i * 32 + o], v2);
        if (lane < 32) z[(size_t)b * 144000 + h * 320 + k * 32 + o] = frelu(v2);
    }
}

__global__ __launch_bounds__(64) void k_t2(
    const float* __restrict__ e2, const float* __restrict__ x1p,
    const float* __restrict__ w1, const float* __restrict__ b1,
    const float* __restrict__ w2, const float* __restrict__ b2,
    float* __restrict__ z)
{
    int blk = blockIdx.x; int b = blk / 50; int h = blk % 50;
    int lane = threadIdx.x;
    const float* er = e2 + (b * 50 + h) * 100;
    float ev[2];
#pragma unroll
    for (int s = 0; s < 2; ++s) { int w = lane + s * 64; ev[s] = (w < 100) ? er[w] : -1e30f; }

    for (int k = 0; k < 10; ++k) {
        float bv = -1e30f; int bi = 0;
#pragma unroll
        for (int s = 0; s < 2; ++s) {
            int w = lane + s * 64;
            if (ev[s] > bv) { bv = ev[s]; bi = w; }
        }
#pragma unroll
        for (int d = 1; d < 64; d <<= 1) {
            float ov = __shfl_xor(bv, d, 64); int oi = __shfl_xor(bi, d, 64);
            if (ov > bv || (ov == bv && oi < bi)) { bv = ov; bi = oi; }
        }
        if ((bi & 63) == lane) ev[bi >> 6] = -1e30f;
        const float* in = x1p + (size_t)((b * 50 + h) * 100 + bi) * 32;
        float v1 = b1[lane];
#pragma unroll
        for (int i = 0; i < 32; ++i) v1 = fmaf(in[i], w1[i * 64 + lane], v1);
        v1 = frelu(v1);
        float v2 = b2[lane];
#pragma unroll
        for (int i = 0; i < 64; ++i) v2 = fmaf(__shfl(v1, i, 64), w2[i * 64 + lane], v2);
        z[(size_t)b * 144000 + 16000 + h * 640 + k * 64 + lane] = frelu(v2);
    }
}

__global__ __launch_bounds__(64) void k_t3(
    const float* __restrict__ e3, const float* __restrict__ x2p,
    const float* __restrict__ w1, const float* __restrict__ b1,
    const float* __restrict__ w2, const float* __restrict__ b2,
    float* __restrict__ z)
{
    int blk = blockIdx.x; int b = blk / 50; int h = blk % 50;
    int lane = threadIdx.x;
    const float* er = e3 + (b * 50 + h) * 20;
    float ev0 = (lane < 20) ? er[lane] : -1e30f;

    for (int k = 0; k < 10; ++k) {
        float bv = ev0; int bi = lane;
#pragma unroll
        for (int d = 1; d < 64; d <<= 1) {
            float ov = __shfl_xor(bv, d, 64); int oi = __shfl_xor(bi, d, 64);
            if (ov > bv || (ov == bv && oi < bi)) { bv = ov; bi = oi; }
        }
        if (bi == lane) ev0 = -1e30f;
        const float* in = x2p + (size_t)((b * 50 + h) * 20 + bi) * 64;
        float v1a = b1[lane], v1b = b1[lane + 64];
#pragma unroll
        for (int i = 0; i < 64; ++i) {
            float a = in[i];
            v1a = fmaf(a, w1[i * 128 + lane], v1a);
            v1b = fmaf(a, w1[i * 128 + lane + 64], v1b);
        }
        v1a = frelu(v1a); v1b = frelu(v1b);
        float v2a = b2[lane], v2b = b2[lane + 64];
#pragma unroll
        for (int i = 0; i < 64; ++i) {
            float s = __shfl(v1a, i, 64);
            v2a = fmaf(s, w2[i * 128 + lane], v2a);
            v2b = fmaf(s, w2[i * 128 + lane + 64], v2b);
        }
#pragma unroll
        for (int i = 0; i < 64; ++i) {
            float s = __shfl(v1b, i, 64);
            v2a = fmaf(s, w2[(i + 64) * 128 + lane], v2a);
            v2b = fmaf(s, w2[(i + 64) * 128 + lane + 64], v2b);
        }
        size_t base = (size_t)b * 144000 + 48000 + h * 1280 + k * 128;
        z[base + lane] = frelu(v2a);
        z[base + lane + 64] = frelu(v2b);
    }
}

// ---------------------------------------------------------------------------
// xf: (B,H,5,128) -> NCHW flatten into z[112000 + c*250 + h*5 + pw]
// ---------------------------------------------------------------------------
__global__ __launch_bounds__(256) void k_xf(const float* __restrict__ x3p, float* __restrict__ z)
{
    int id = blockIdx.x * 256 + threadIdx.x;         // 2,048,000
    int b = id / 32000; int r = id % 32000;
    int c = r / 250; int hw = r % 250; int h = hw / 5; int pw = hw % 5;
    z[(size_t)b * 144000 + 112000 + r] = x3p[(size_t)((b * 50 + h) * 5 + pw) * 128 + c];
}

// ---------------------------------------------------------------------------
// Skinny GEMM: out_part[kc][n][m] = sum over K-chunk of A[m][k]*W[k][n]
// lane = m (batch), weights wave-uniform -> scalar loads + v_fmac(s,v).
// A staged transposed into LDS (pad 65 to dodge bank conflicts).
// ---------------------------------------------------------------------------
__global__ __launch_bounds__(256) void k_gemm(
    const float* __restrict__ A, const float* __restrict__ W,
    float* __restrict__ part, int K, int N, int KC)
{
    __shared__ float zls[64 * 65];
    int tid = threadIdx.x;
    int wave = tid >> 6, lane = tid & 63;
    int nb = blockIdx.x, kc = blockIdx.y;
    int n_base = nb * 256 + wave * 64;
    float acc[64];
#pragma unroll
    for (int n = 0; n < 64; ++n) acc[n] = 0.f;

    int row = tid >> 2, c4 = tid & 3;
    int kend = kc * KC + KC;
    for (int k0 = kc * KC; k0 < kend; k0 += 64) {
        const float4* src = (const float4*)(A + (size_t)row * K + k0 + c4 * 16);
#pragma unroll
        for (int u = 0; u < 4; ++u) {
            float4 v = src[u];
            zls[(c4 * 16 + u * 4 + 0) * 65 + row] = v.x;
            zls[(c4 * 16 + u * 4 + 1) * 65 + row] = v.y;
            zls[(c4 * 16 + u * 4 + 2) * 65 + row] = v.z;
            zls[(c4 * 16 + u * 4 + 3) * 65 + row] = v.w;
        }
        __syncthreads();
#pragma unroll 1
        for (int kk = 0; kk < 64; ++kk) {
            float zv = zls[kk * 65 + lane];
            const float* wr = W + (size_t)(k0 + kk) * N + n_base;
#pragma unroll
            for (int n = 0; n < 64; ++n) acc[n] = fmaf(wr[n], zv, acc[n]);
        }
        __syncthreads();
    }
    float* p = part + ((size_t)kc * N + n_base) * 64 + lane;
#pragma unroll
    for (int n = 0; n < 64; ++n) p[(size_t)n * 64] = acc[n];
}

__global__ __launch_bounds__(256) void k_red(
    const float* __restrict__ part, const float* __restrict__ bias,
    float* __restrict__ out, int N, int C, int doRelu)
{
    int id = blockIdx.x * 256 + threadIdx.x;         // N*64
    int m = id & 63, n = id >> 6;
    float s = 0.f;
    for (int c = 0; c < C; ++c) s += part[((size_t)c * N + n) * 64 + m];
    s += bias[n];
    if (doRelu) s = frelu(s);
    out[(size_t)m * N + n] = s;
}

__global__ __launch_bounds__(256) void k_fc3(
    const float* __restrict__ h2, const float* __restrict__ w3,
    const float* __restrict__ b3, float* __restrict__ out)
{
    int id = blockIdx.x * 256 + threadIdx.x;
    if (id >= 64 * 150) return;
    int m = id / 150, o = id % 150;
    float s = b3[o];
    for (int k = 0; k < 1024; ++k) s = fmaf(h2[m * 1024 + k], w3[k * 150 + o], s);
    out[id] = s;
}

// ---------------------------------------------------------------------------
extern "C" void kernel_launch(void* const* d_in, const int* in_sizes, int n_in,
                              void* d_out, int out_size, void* d_ws, size_t ws_size,
                              hipStream_t stream) {
    const float* X    = (const float*)d_in[0];
    const float* c1w1 = (const float*)d_in[1];
    const float* c1b1 = (const float*)d_in[2];
    const float* c1w2 = (const float*)d_in[3];
    const float* c1b2 = (const float*)d_in[4];
    const float* a1W  = (const float*)d_in[5];
    const float* a1b  = (const float*)d_in[6];
    const float* c2w1 = (const float*)d_in[7];
    const float* c2b1 = (const float*)d_in[8];
    const float* c2w2 = (const float*)d_in[9];
    const float* c2b2 = (const float*)d_in[10];
    const float* a2W  = (const float*)d_in[11];
    const float* a2b  = (const float*)d_in[12];
    const float* c3w1 = (const float*)d_in[13];
    const float* c3b1 = (const float*)d_in[14];
    const float* c3w2 = (const float*)d_in[15];
    const float* c3b2 = (const float*)d_in[16];
    const float* a3W  = (const float*)d_in[17];
    const float* a3b  = (const float*)d_in[18];
    const float* fc1w = (const float*)d_in[19];
    const float* fc1b = (const float*)d_in[20];
    const float* fc2w = (const float*)d_in[21];
    const float* fc2b = (const float*)d_in[22];
    const float* fc3w = (const float*)d_in[23];
    const float* fc3b = (const float*)d_in[24];

    float* ws  = (float*)d_ws;
    float* x1p = ws;                       // 10,240,000
    float* x2p = ws + 10240000;            //  4,096,000
    float* x3p = ws + 14336000;            //  2,048,000
    float* e1  = ws + 16384000;            //  1,600,000
    float* e2  = ws + 17984000;            //    320,000
    float* e3  = ws + 18304000;            //     64,000
    float* z   = ws + 18368000;            //  9,216,000
    float* p1  = ws + 27584000;            //  8,192,000 (125*1024*64)
    float* h1  = ws + 35776000;            //     65,536
    float* p2  = ws + 35841536;            //  1,048,576 (16*1024*64)
    float* h2  = ws + 36890112;            //     65,536  (end 36,955,648 floats)

    k_s1<<<1250, 256, 0, stream>>>(X, c1w1, c1b1, c1w2, c1b2, a1W, a1b, x1p, e1);
    k_t1<<<3200, 64, 0, stream>>>(e1, X, c1w1, c1b1, c1w2, c1b2, z);
    k_s2<<<1000, 256, 0, stream>>>(x1p, c2w1, c2b1, c2w2, c2b2, a2W, a2b, x2p, e2);
    k_t2<<<3200, 64, 0, stream>>>(e2, x1p, c2w1, c2b1, c2w2, c2b2, z);
    k_s3<<<500, 256, 0, stream>>>(x2p, c3w1, c3b1, c3w2, c3b2, a3W, a3b, x3p, e3);
    k_t3<<<3200, 64, 0, stream>>>(e3, x2p, c3w1, c3b1, c3w2, c3b2, z);
    k_xf<<<8000, 256, 0, stream>>>(x3p, z);

    k_gemm<<<dim3(4, 125), 256, 0, stream>>>(z, fc1w, p1, 144000, 1024, 1152);
    k_red<<<256, 256, 0, stream>>>(p1, fc1b, h1, 1024, 125, 1);
    k_gemm<<<dim3(4, 16), 256, 0, stream>>>(h1, fc2w, p2, 1024, 1024, 64);
    k_red<<<256, 256, 0, stream>>>(p2, fc2b, h2, 1024, 16, 0);
    k_fc3<<<38, 256, 0, stream>>>(h2, fc3w, fc3b, (float*)d_out);
}

// Round 3
// 6793.769 us; speedup vs baseline: 1.0017x; 1.0017x over previous
//
#include <hip/hip_runtime.h>
#include <math.h>

#define DEV __device__ __forceinline__
DEV float frelu(float x) { return x > 0.f ? x : 0.f; }

// ---------------------------------------------------------------------------
// Stage 1: x(B,50,500,3) -> conv3->32 relu -> conv32->32 relu ; e1 = tanh(att)
// pooled max over 5 -> x1p(B,50,100,32). Thread = one pool group (5 pixels).
// Weights read via wave-uniform indices -> scalar loads; activations in regs.
// ---------------------------------------------------------------------------
__global__ __launch_bounds__(256) void k_s1(
    const float* __restrict__ x,
    const float* __restrict__ w1, const float* __restrict__ b1,
    const float* __restrict__ w2, const float* __restrict__ b2,
    const float* __restrict__ aW, const float* __restrict__ ab,
    float* __restrict__ x1p, float* __restrict__ e1)
{
    int T = blockIdx.x * 256 + threadIdx.x;          // 320000 pool groups
    int b = T / 5000; int r = T % 5000; int h = r / 100; int pw = r % 100;
    const float* xrow = x + (size_t)((b * 50 + h) * 500) * 3;

    float vmax[32];
#pragma unroll
    for (int o = 0; o < 32; ++o) vmax[o] = 0.f;

#pragma unroll 1
    for (int j = 0; j < 5; ++j) {
        int w = pw * 5 + j;
        float x0 = xrow[w * 3 + 0], x1 = xrow[w * 3 + 1], x2 = xrow[w * 3 + 2];
        float v1[32];
#pragma unroll
        for (int o = 0; o < 32; ++o)
            v1[o] = frelu(fmaf(x0, w1[o], fmaf(x1, w1[32 + o], fmaf(x2, w1[64 + o], b1[o]))));
        float v2[32];
#pragma unroll
        for (int o = 0; o < 32; ++o) v2[o] = b2[o];
#pragma unroll
        for (int i = 0; i < 32; ++i) {
            float a = v1[i];
#pragma unroll
            for (int o = 0; o < 32; ++o) v2[o] = fmaf(a, w2[i * 32 + o], v2[o]);
        }
        float e = ab[h * 500 + w];
#pragma unroll
        for (int o = 0; o < 32; ++o) {
            float t = frelu(v2[o]);
            vmax[o] = fmaxf(vmax[o], t);
            e = fmaf(t, aW[h * 32 + o], e);
        }
        e1[(b * 50 + h) * 500 + w] = tanhf(e);
    }
    float* dst = x1p + (size_t)((b * 50 + h) * 100 + pw) * 32;
#pragma unroll
    for (int o = 0; o < 32; ++o) dst[o] = vmax[o];
}

// ---------------------------------------------------------------------------
// Stage 2: x1p -> conv32->64 relu -> conv64->64 relu ; e2 ; pool5 -> x2p
// Thread = (pool group, 16-channel slice q in 0..3). v1 shared via LDS.
// ---------------------------------------------------------------------------
__global__ __launch_bounds__(256) void k_s2(
    const float* __restrict__ x1p,
    const float* __restrict__ w1, const float* __restrict__ b1,
    const float* __restrict__ w2, const float* __restrict__ b2,
    const float* __restrict__ aW, const float* __restrict__ ab,
    float* __restrict__ x2p, float* __restrict__ e2)
{
    __shared__ float v1buf[64][66];
    int tid = threadIdx.x;
    int T = blockIdx.x * 256 + tid;
    int q = T & 3; int G = T >> 2;                   // 256000 threads, 64000 groups
    int b = G / 1000; int rr = G % 1000; int h = rr / 20; int pw = rr % 20;
    int gl = tid >> 2;

    float vmax[16];
#pragma unroll
    for (int o = 0; o < 16; ++o) vmax[o] = 0.f;

#pragma unroll 1
    for (int j = 0; j < 5; ++j) {
        int w = pw * 5 + j;
        const float* in = x1p + (size_t)((b * 50 + h) * 100 + w) * 32;
        float v1[16];
#pragma unroll
        for (int o = 0; o < 16; ++o) v1[o] = b1[q * 16 + o];
#pragma unroll
        for (int i = 0; i < 32; ++i) {
            float a = in[i];
#pragma unroll
            for (int o = 0; o < 16; ++o) v1[o] = fmaf(a, w1[i * 64 + q * 16 + o], v1[o]);
        }
#pragma unroll
        for (int o = 0; o < 16; ++o) v1buf[gl][q * 16 + o] = frelu(v1[o]);
        __syncthreads();
        float v2[16];
#pragma unroll
        for (int o = 0; o < 16; ++o) v2[o] = b2[q * 16 + o];
#pragma unroll
        for (int i = 0; i < 64; ++i) {
            float a = v1buf[gl][i];
#pragma unroll
            for (int o = 0; o < 16; ++o) v2[o] = fmaf(a, w2[i * 64 + q * 16 + o], v2[o]);
        }
        float ep = 0.f;
#pragma unroll
        for (int o = 0; o < 16; ++o) {
            float t = frelu(v2[o]);
            vmax[o] = fmaxf(vmax[o], t);
            ep = fmaf(t, aW[h * 64 + q * 16 + o], ep);
        }
        ep += __shfl_xor(ep, 1, 64);
        ep += __shfl_xor(ep, 2, 64);
        if (q == 0) e2[(b * 50 + h) * 100 + w] = tanhf(ep + ab[h * 100 + w]);
        __syncthreads();
    }
    float* dst = x2p + (size_t)((b * 50 + h) * 20 + pw) * 64 + q * 16;
#pragma unroll
    for (int o = 0; o < 16; ++o) dst[o] = vmax[o];
}

// ---------------------------------------------------------------------------
// Stage 3: x2p -> conv64->128 relu -> conv128->128 relu ; e3 ; pool4 -> x3p
// Thread = (pool group, 16-channel slice q in 0..7).
// ---------------------------------------------------------------------------
__global__ __launch_bounds__(256) void k_s3(
    const float* __restrict__ x2p,
    const float* __restrict__ w1, const float* __restrict__ b1,
    const float* __restrict__ w2, const float* __restrict__ b2,
    const float* __restrict__ aW, const float* __restrict__ ab,
    float* __restrict__ x3p, float* __restrict__ e3)
{
    __shared__ float v1buf[32][130];
    int tid = threadIdx.x;
    int T = blockIdx.x * 256 + tid;
    int q = T & 7; int G = T >> 3;                   // 128000 threads, 16000 groups
    int b = G / 250; int rr = G % 250; int h = rr / 5; int pw = rr % 5;
    int gl = tid >> 3;

    float vmax[16];
#pragma unroll
    for (int o = 0; o < 16; ++o) vmax[o] = 0.f;

#pragma unroll 1
    for (int j = 0; j < 4; ++j) {
        int w = pw * 4 + j;
        const float* in = x2p + (size_t)((b * 50 + h) * 20 + w) * 64;
        float v1[16];
#pragma unroll
        for (int o = 0; o < 16; ++o) v1[o] = b1[q * 16 + o];
#pragma unroll
        for (int i = 0; i < 64; ++i) {
            float a = in[i];
#pragma unroll
            for (int o = 0; o < 16; ++o) v1[o] = fmaf(a, w1[i * 128 + q * 16 + o], v1[o]);
        }
#pragma unroll
        for (int o = 0; o < 16; ++o) v1buf[gl][q * 16 + o] = frelu(v1[o]);
        __syncthreads();
        float v2[16];
#pragma unroll
        for (int o = 0; o < 16; ++o) v2[o] = b2[q * 16 + o];
#pragma unroll
        for (int i = 0; i < 128; ++i) {
            float a = v1buf[gl][i];
#pragma unroll
            for (int o = 0; o < 16; ++o) v2[o] = fmaf(a, w2[i * 128 + q * 16 + o], v2[o]);
        }
        float ep = 0.f;
#pragma unroll
        for (int o = 0; o < 16; ++o) {
            float t = frelu(v2[o]);
            vmax[o] = fmaxf(vmax[o], t);
            ep = fmaf(t, aW[h * 128 + q * 16 + o], ep);
        }
        ep += __shfl_xor(ep, 1, 64);
        ep += __shfl_xor(ep, 2, 64);
        ep += __shfl_xor(ep, 4, 64);
        if (q == 0) e3[(b * 50 + h) * 20 + w] = tanhf(ep + ab[h * 20 + w]);
        __syncthreads();
    }
    float* dst = x3p + (size_t)((b * 50 + h) * 5 + pw) * 128 + q * 16;
#pragma unroll
    for (int o = 0; o < 16; ++o) dst[o] = vmax[o];
}

// ---------------------------------------------------------------------------
// Top-k (k=10, jax.lax.top_k semantics: sorted desc, ties -> lower index)
// + gather: recompute conv features at the selected pixels, write into z.
// One wave per (b,h) row.
// ---------------------------------------------------------------------------
__global__ __launch_bounds__(64) void k_t1(
    const float* __restrict__ e1, const float* __restrict__ x,
    const float* __restrict__ w1, const float* __restrict__ b1,
    const float* __restrict__ w2, const float* __restrict__ b2,
    float* __restrict__ z)
{
    int blk = blockIdx.x; int b = blk / 50; int h = blk % 50;
    int lane = threadIdx.x;
    const float* er = e1 + (b * 50 + h) * 500;
    float ev[8];
#pragma unroll
    for (int s = 0; s < 8; ++s) { int w = lane + s * 64; ev[s] = (w < 500) ? er[w] : -1e30f; }

    for (int k = 0; k < 10; ++k) {
        float bv = -1e30f; int bi = 0;
#pragma unroll
        for (int s = 0; s < 8; ++s) {
            int w = lane + s * 64;
            if (ev[s] > bv) { bv = ev[s]; bi = w; }
        }
#pragma unroll
        for (int d = 1; d < 64; d <<= 1) {
            float ov = __shfl_xor(bv, d, 64); int oi = __shfl_xor(bi, d, 64);
            if (ov > bv || (ov == bv && oi < bi)) { bv = ov; bi = oi; }
        }
        if ((bi & 63) == lane) ev[bi >> 6] = -1e30f;
        // gather: recompute x1 features at pixel bi
        const float* px = x + (size_t)((b * 50 + h) * 500 + bi) * 3;
        float x0 = px[0], x1 = px[1], x2 = px[2];
        int o = lane & 31;
        float v1 = frelu(fmaf(x0, w1[o], fmaf(x1, w1[32 + o], fmaf(x2, w1[64 + o], b1[o]))));
        float v2 = b2[o];
#pragma unroll
        for (int i = 0; i < 32; ++i) v2 = fmaf(__shfl(v1, i, 64), w2[i * 32 + o], v2);
        if (lane < 32) z[(size_t)b * 144000 + h * 320 + k * 32 + o] = frelu(v2);
    }
}

__global__ __launch_bounds__(64) void k_t2(
    const float* __restrict__ e2, const float* __restrict__ x1p,
    const float* __restrict__ w1, const float* __restrict__ b1,
    const float* __restrict__ w2, const float* __restrict__ b2,
    float* __restrict__ z)
{
    int blk = blockIdx.x; int b = blk / 50; int h = blk % 50;
    int lane = threadIdx.x;
    const float* er = e2 + (b * 50 + h) * 100;
    float ev[2];
#pragma unroll
    for (int s = 0; s < 2; ++s) { int w = lane + s * 64; ev[s] = (w < 100) ? er[w] : -1e30f; }

    for (int k = 0; k < 10; ++k) {
        float bv = -1e30f; int bi = 0;
#pragma unroll
        for (int s = 0; s < 2; ++s) {
            int w = lane + s * 64;
            if (ev[s] > bv) { bv = ev[s]; bi = w; }
        }
#pragma unroll
        for (int d = 1; d < 64; d <<= 1) {
            float ov = __shfl_xor(bv, d, 64); int oi = __shfl_xor(bi, d, 64);
            if (ov > bv || (ov == bv && oi < bi)) { bv = ov; bi = oi; }
        }
        if ((bi & 63) == lane) ev[bi >> 6] = -1e30f;
        const float* in = x1p + (size_t)((b * 50 + h) * 100 + bi) * 32;
        float v1 = b1[lane];
#pragma unroll
        for (int i = 0; i < 32; ++i) v1 = fmaf(in[i], w1[i * 64 + lane], v1);
        v1 = frelu(v1);
        float v2 = b2[lane];
#pragma unroll
        for (int i = 0; i < 64; ++i) v2 = fmaf(__shfl(v1, i, 64), w2[i * 64 + lane], v2);
        z[(size_t)b * 144000 + 16000 + h * 640 + k * 64 + lane] = frelu(v2);
    }
}

__global__ __launch_bounds__(64) void k_t3(
    const float* __restrict__ e3, const float* __restrict__ x2p,
    const float* __restrict__ w1, const float* __restrict__ b1,
    const float* __restrict__ w2, const float* __restrict__ b2,
    float* __restrict__ z)
{
    int blk = blockIdx.x; int b = blk / 50; int h = blk % 50;
    int lane = threadIdx.x;
    const float* er = e3 + (b * 50 + h) * 20;
    float ev0 = (lane < 20) ? er[lane] : -1e30f;

    for (int k = 0; k < 10; ++k) {
        float bv = ev0; int bi = lane;
#pragma unroll
        for (int d = 1; d < 64; d <<= 1) {
            float ov = __shfl_xor(bv, d, 64); int oi = __shfl_xor(bi, d, 64);
            if (ov > bv || (ov == bv && oi < bi)) { bv = ov; bi = oi; }
        }
        if (bi == lane) ev0 = -1e30f;
        const float* in = x2p + (size_t)((b * 50 + h) * 20 + bi) * 64;
        float v1a = b1[lane], v1b = b1[lane + 64];
#pragma unroll
        for (int i = 0; i < 64; ++i) {
            float a = in[i];
            v1a = fmaf(a, w1[i * 128 + lane], v1a);
            v1b = fmaf(a, w1[i * 128 + lane + 64], v1b);
        }
        v1a = frelu(v1a); v1b = frelu(v1b);
        float v2a = b2[lane], v2b = b2[lane + 64];
#pragma unroll
        for (int i = 0; i < 64; ++i) {
            float s = __shfl(v1a, i, 64);
            v2a = fmaf(s, w2[i * 128 + lane], v2a);
            v2b = fmaf(s, w2[i * 128 + lane + 64], v2b);
        }
#pragma unroll
        for (int i = 0; i < 64; ++i) {
            float s = __shfl(v1b, i, 64);
            v2a = fmaf(s, w2[(i + 64) * 128 + lane], v2a);
            v2b = fmaf(s, w2[(i + 64) * 128 + lane + 64], v2b);
        }
        size_t base = (size_t)b * 144000 + 48000 + h * 1280 + k * 128;
        z[base + lane] = frelu(v2a);
        z[base + lane + 64] = frelu(v2b);
    }
}

// ---------------------------------------------------------------------------
// xf: (B,H,5,128) -> NCHW flatten into z[112000 + c*250 + h*5 + pw]
// ---------------------------------------------------------------------------
__global__ __launch_bounds__(256) void k_xf(const float* __restrict__ x3p, float* __restrict__ z)
{
    int id = blockIdx.x * 256 + threadIdx.x;         // 2,048,000
    int b = id / 32000; int r = id % 32000;
    int c = r / 250; int hw = r % 250; int h = hw / 5; int pw = hw % 5;
    z[(size_t)b * 144000 + 112000 + r] = x3p[(size_t)((b * 50 + h) * 5 + pw) * 128 + c];
}

// ---------------------------------------------------------------------------
// Skinny GEMM: out_part[kc][n][m] = sum over K-chunk of A[m][k]*W[k][n]
// lane = m (batch), weights wave-uniform -> scalar loads + v_fmac(s,v).
// A staged transposed into LDS (pad 65 to dodge bank conflicts).
// ---------------------------------------------------------------------------
__global__ __launch_bounds__(256) void k_gemm(
    const float* __restrict__ A, const float* __restrict__ W,
    float* __restrict__ part, int K, int N, int KC)
{
    __shared__ float zls[64 * 65];
    int tid = threadIdx.x;
    int wave = tid >> 6, lane = tid & 63;
    int nb = blockIdx.x, kc = blockIdx.y;
    int n_base = nb * 256 + wave * 64;
    float acc[64];
#pragma unroll
    for (int n = 0; n < 64; ++n) acc[n] = 0.f;

    int row = tid >> 2, c4 = tid & 3;
    int kend = kc * KC + KC;
    for (int k0 = kc * KC; k0 < kend; k0 += 64) {
        const float4* src = (const float4*)(A + (size_t)row * K + k0 + c4 * 16);
#pragma unroll
        for (int u = 0; u < 4; ++u) {
            float4 v = src[u];
            zls[(c4 * 16 + u * 4 + 0) * 65 + row] = v.x;
            zls[(c4 * 16 + u * 4 + 1) * 65 + row] = v.y;
            zls[(c4 * 16 + u * 4 + 2) * 65 + row] = v.z;
            zls[(c4 * 16 + u * 4 + 3) * 65 + row] = v.w;
        }
        __syncthreads();
#pragma unroll 1
        for (int kk = 0; kk < 64; ++kk) {
            float zv = zls[kk * 65 + lane];
            const float* wr = W + (size_t)(k0 + kk) * N + n_base;
#pragma unroll
            for (int n = 0; n < 64; ++n) acc[n] = fmaf(wr[n], zv, acc[n]);
        }
        __syncthreads();
    }
    float* p = part + ((size_t)kc * N + n_base) * 64 + lane;
#pragma unroll
    for (int n = 0; n < 64; ++n) p[(size_t)n * 64] = acc[n];
}

__global__ __launch_bounds__(256) void k_red(
    const float* __restrict__ part, const float* __restrict__ bias,
    float* __restrict__ out, int N, int C, int doRelu)
{
    int id = blockIdx.x * 256 + threadIdx.x;         // N*64
    int m = id & 63, n = id >> 6;
    float s = 0.f;
    for (int c = 0; c < C; ++c) s += part[((size_t)c * N + n) * 64 + m];
    s += bias[n];
    if (doRelu) s = frelu(s);
    out[(size_t)m * N + n] = s;
}

__global__ __launch_bounds__(256) void k_fc3(
    const float* __restrict__ h2, const float* __restrict__ w3,
    const float* __restrict__ b3, float* __restrict__ out)
{
    int id = blockIdx.x * 256 + threadIdx.x;
    if (id >= 64 * 150) return;
    int m = id / 150, o = id % 150;
    float s = b3[o];
    for (int k = 0; k < 1024; ++k) s = fmaf(h2[m * 1024 + k], w3[k * 150 + o], s);
    out[id] = s;
}

// ---------------------------------------------------------------------------
extern "C" void kernel_launch(void* const* d_in, const int* in_sizes, int n_in,
                              void* d_out, int out_size, void* d_ws, size_t ws_size,
                              hipStream_t stream) {
    const float* X    = (const float*)d_in[0];
    const float* c1w1 = (const float*)d_in[1];
    const float* c1b1 = (const float*)d_in[2];
    const float* c1w2 = (const float*)d_in[3];
    const float* c1b2 = (const float*)d_in[4];
    const float* a1W  = (const float*)d_in[5];
    const float* a1b  = (const float*)d_in[6];
    const float* c2w1 = (const float*)d_in[7];
    const float* c2b1 = (const float*)d_in[8];
    const float* c2w2 = (const float*)d_in[9];
    const float* c2b2 = (const float*)d_in[10];
    const float* a2W  = (const float*)d_in[11];
    const float* a2b  = (const float*)d_in[12];
    const float* c3w1 = (const float*)d_in[13];
    const float* c3b1 = (const float*)d_in[14];
    const float* c3w2 = (const float*)d_in[15];
    const float* c3b2 = (const float*)d_in[16];
    const float* a3W  = (const float*)d_in[17];
    const float* a3b  = (const float*)d_in[18];
    const float* fc1w = (const float*)d_in[19];
    const float* fc1b = (const float*)d_in[20];
    const float* fc2w = (const float*)d_in[21];
    const float* fc2b = (const float*)d_in[22];
    const float* fc3w = (const float*)d_in[23];
    const float* fc3b = (const float*)d_in[24];

    float* ws  = (float*)d_ws;
    float* x1p = ws;                       // 10,240,000
    float* x2p = ws + 10240000;            //  4,096,000
    float* x3p = ws + 14336000;            //  2,048,000
    float* e1  = ws + 16384000;            //  1,600,000
    float* e2  = ws + 17984000;            //    320,000
    float* e3  = ws + 18304000;            //     64,000
    float* z   = ws + 18368000;            //  9,216,000
    float* p1  = ws + 27584000;            //  8,192,000 (125*1024*64)
    float* h1  = ws + 35776000;            //     65,536
    float* p2  = ws + 35841536;            //  1,048,576 (16*1024*64)
    float* h2  = ws + 36890112;            //     65,536  (end 36,955,648 floats)

    k_s1<<<1250, 256, 0, stream>>>(X, c1w1, c1b1, c1w2, c1b2, a1W, a1b, x1p, e1);
    k_t1<<<3200, 64, 0, stream>>>(e1, X, c1w1, c1b1, c1w2, c1b2, z);
    k_s2<<<1000, 256, 0, stream>>>(x1p, c2w1, c2b1, c2w2, c2b2, a2W, a2b, x2p, e2);
    k_t2<<<3200, 64, 0, stream>>>(e2, x1p, c2w1, c2b1, c2w2, c2b2, z);
    k_s3<<<500, 256, 0, stream>>>(x2p, c3w1, c3b1, c3w2, c3b2, a3W, a3b, x3p, e3);
    k_t3<<<3200, 64, 0, stream>>>(e3, x2p, c3w1, c3b1, c3w2, c3b2, z);
    k_xf<<<8000, 256, 0, stream>>>(x3p, z);

    k_gemm<<<dim3(4, 125), 256, 0, stream>>>(z, fc1w, p1, 144000, 1024, 1152);
    k_red<<<256, 256, 0, stream>>>(p1, fc1b, h1, 1024, 125, 1);
    k_gemm<<<dim3(4, 16), 256, 0, stream>>>(h1, fc2w, p2, 1024, 1024, 64);
    k_red<<<256, 256, 0, stream>>>(p2, fc2b, h2, 1024, 16, 0);
    k_fc3<<<38, 256, 0, stream>>>(h2, fc3w, fc3b, (float*)d_out);
}

// Round 4
// 1317.692 us; speedup vs baseline: 5.1646x; 5.1558x over previous
//
#include <hip/hip_runtime.h>
#include <math.h>

#define DEV __device__ __forceinline__
DEV float frelu(float x) { return x > 0.f ? x : 0.f; }

// ===========================================================================
// Stage 1: conv 3->32 relu -> conv 32->32 relu ; e1 = tanh(att) ; pool5 -> x1p
// WREG form: wave = 2 pool-groups (one per 32-lane half), lane = out channel.
// Weights live in per-lane registers; v1 crosses channels via per-wave LDS
// slice (same-address broadcast reads, conflict-free). No barriers needed:
// waves use disjoint LDS slices; within-wave RAW ordered by lgkmcnt.
// ===========================================================================
__global__ __launch_bounds__(256) void k_s1(
    const float* __restrict__ x,
    const float* __restrict__ w1, const float* __restrict__ b1,
    const float* __restrict__ w2, const float* __restrict__ b2,
    const float* __restrict__ aW, const float* __restrict__ ab,
    float* __restrict__ x1p, float* __restrict__ e1)
{
    __shared__ float v1s[4][2][32];
    int tid = threadIdx.x;
    int wv = tid >> 6, lane = tid & 63;
    int half = lane >> 5, o = lane & 31;
    int gw = blockIdx.x * 4 + wv;            // 160000 wave-slots
    int g = gw * 2 + half;                   // pool group 0..319999
    int b = g / 5000, r = g % 5000, h = r / 100, pw = r % 100;

    float W1c0 = w1[o], W1c1 = w1[32 + o], W1c2 = w1[64 + o], B1 = b1[o];
    float W2[32];
#pragma unroll
    for (int i = 0; i < 32; ++i) W2[i] = w2[i * 32 + o];
    float B2 = b2[o], AWo = aW[h * 32 + o];
    float vmax = 0.f;
    const float* xrow = x + (size_t)((b * 50 + h) * 500) * 3;
    float* vs = &v1s[wv][half][0];

#pragma unroll 1
    for (int j = 0; j < 5; ++j) {
        int w = pw * 5 + j;
        float x0 = xrow[w * 3 + 0], x1v = xrow[w * 3 + 1], x2v = xrow[w * 3 + 2];
        float v1 = frelu(fmaf(x0, W1c0, fmaf(x1v, W1c1, fmaf(x2v, W1c2, B1))));
        vs[o] = v1;
        float a2 = B2;
#pragma unroll
        for (int i = 0; i < 32; i += 4) {
            float4 v4 = *(const float4*)&vs[i];
            a2 = fmaf(v4.x, W2[i + 0], a2);
            a2 = fmaf(v4.y, W2[i + 1], a2);
            a2 = fmaf(v4.z, W2[i + 2], a2);
            a2 = fmaf(v4.w, W2[i + 3], a2);
        }
        float t = frelu(a2);
        vmax = fmaxf(vmax, t);
        float ep = t * AWo;
        ep += __shfl_xor(ep, 1, 64);
        ep += __shfl_xor(ep, 2, 64);
        ep += __shfl_xor(ep, 4, 64);
        ep += __shfl_xor(ep, 8, 64);
        ep += __shfl_xor(ep, 16, 64);
        if (o == 0) e1[(b * 50 + h) * 500 + w] = tanhf(ep + ab[h * 500 + w]);
    }
    x1p[(size_t)g * 32 + o] = vmax;
}

// ===========================================================================
// Stage 2: conv 32->64 relu -> conv 64->64 relu ; e2 ; pool5 -> x2p
// WREG: wave = 1 pool-group, lane = out channel (64). W1:32 + W2:64 regs.
// conv1 acts via same-address global float4 broadcast loads.
// ===========================================================================
__global__ __launch_bounds__(256) void k_s2(
    const float* __restrict__ x1p,
    const float* __restrict__ w1, const float* __restrict__ b1,
    const float* __restrict__ w2, const float* __restrict__ b2,
    const float* __restrict__ aW, const float* __restrict__ ab,
    float* __restrict__ x2p, float* __restrict__ e2)
{
    __shared__ float v1s[4][64];
    int tid = threadIdx.x;
    int wv = tid >> 6, o = tid & 63;
    int g = blockIdx.x * 4 + wv;             // 64000 groups
    int b = g / 1000, r = g % 1000, h = r / 20, pw = r % 20;

    float W1[32];
#pragma unroll
    for (int i = 0; i < 32; ++i) W1[i] = w1[i * 64 + o];
    float W2[64];
#pragma unroll
    for (int i = 0; i < 64; ++i) W2[i] = w2[i * 64 + o];
    float B1 = b1[o], B2 = b2[o], AWo = aW[h * 64 + o];
    float vmax = 0.f;
    float* vs = &v1s[wv][0];

#pragma unroll 1
    for (int j = 0; j < 5; ++j) {
        int w = pw * 5 + j;
        const float* in = x1p + (size_t)((b * 50 + h) * 100 + w) * 32;
        float a1 = B1;
#pragma unroll
        for (int i = 0; i < 32; i += 4) {
            float4 a4 = *(const float4*)&in[i];
            a1 = fmaf(a4.x, W1[i + 0], a1);
            a1 = fmaf(a4.y, W1[i + 1], a1);
            a1 = fmaf(a4.z, W1[i + 2], a1);
            a1 = fmaf(a4.w, W1[i + 3], a1);
        }
        vs[o] = frelu(a1);
        float a2 = B2;
#pragma unroll
        for (int i = 0; i < 64; i += 4) {
            float4 v4 = *(const float4*)&vs[i];
            a2 = fmaf(v4.x, W2[i + 0], a2);
            a2 = fmaf(v4.y, W2[i + 1], a2);
            a2 = fmaf(v4.z, W2[i + 2], a2);
            a2 = fmaf(v4.w, W2[i + 3], a2);
        }
        float t = frelu(a2);
        vmax = fmaxf(vmax, t);
        float ep = t * AWo;
        ep += __shfl_xor(ep, 1, 64);
        ep += __shfl_xor(ep, 2, 64);
        ep += __shfl_xor(ep, 4, 64);
        ep += __shfl_xor(ep, 8, 64);
        ep += __shfl_xor(ep, 16, 64);
        ep += __shfl_xor(ep, 32, 64);
        if (o == 0) e2[(b * 50 + h) * 100 + w] = tanhf(ep + ab[h * 100 + w]);
    }
    x2p[(size_t)g * 64 + o] = vmax;
}

// ===========================================================================
// Stage 3: conv 64->128 relu -> conv 128->128 relu ; e3 ; pool4 -> x3p
// WREG: wave-PAIR covers 128 out channels (o = (wave&1)*64 + lane);
// block 256 = 2 pixel-slots. W1:64 + W2:128 regs. Cross-wave v1 share via
// LDS + __syncthreads (all waves have identical trip counts).
// ===========================================================================
__global__ __launch_bounds__(256) void k_s3(
    const float* __restrict__ x2p,
    const float* __restrict__ w1, const float* __restrict__ b1,
    const float* __restrict__ w2, const float* __restrict__ b2,
    const float* __restrict__ aW, const float* __restrict__ ab,
    float* __restrict__ x3p, float* __restrict__ e3)
{
    __shared__ float v1s[2][128];
    __shared__ float epart[2][2];
    int tid = threadIdx.x;
    int wv = tid >> 6, lane = tid & 63;
    int slot = wv >> 1, oh = wv & 1;
    int o = oh * 64 + lane;
    int g = blockIdx.x * 2 + slot;           // 16000 groups
    int b = g / 250, r = g % 250, h = r / 5, pw = r % 5;

    float W1[64];
#pragma unroll
    for (int i = 0; i < 64; ++i) W1[i] = w1[i * 128 + o];
    float W2[128];
#pragma unroll
    for (int i = 0; i < 128; ++i) W2[i] = w2[i * 128 + o];
    float B1 = b1[o], B2 = b2[o], AWo = aW[h * 128 + o];
    float vmax = 0.f;

#pragma unroll 1
    for (int j = 0; j < 4; ++j) {
        int w = pw * 4 + j;
        const float* in = x2p + (size_t)((b * 50 + h) * 20 + w) * 64;
        float a1 = B1;
#pragma unroll
        for (int i = 0; i < 64; i += 4) {
            float4 a4 = *(const float4*)&in[i];
            a1 = fmaf(a4.x, W1[i + 0], a1);
            a1 = fmaf(a4.y, W1[i + 1], a1);
            a1 = fmaf(a4.z, W1[i + 2], a1);
            a1 = fmaf(a4.w, W1[i + 3], a1);
        }
        v1s[slot][o] = frelu(a1);
        __syncthreads();
        float a2 = B2;
#pragma unroll
        for (int i = 0; i < 128; i += 4) {
            float4 v4 = *(const float4*)&v1s[slot][i];
            a2 = fmaf(v4.x, W2[i + 0], a2);
            a2 = fmaf(v4.y, W2[i + 1], a2);
            a2 = fmaf(v4.z, W2[i + 2], a2);
            a2 = fmaf(v4.w, W2[i + 3], a2);
        }
        float t = frelu(a2);
        vmax = fmaxf(vmax, t);
        float ep = t * AWo;
        ep += __shfl_xor(ep, 1, 64);
        ep += __shfl_xor(ep, 2, 64);
        ep += __shfl_xor(ep, 4, 64);
        ep += __shfl_xor(ep, 8, 64);
        ep += __shfl_xor(ep, 16, 64);
        ep += __shfl_xor(ep, 32, 64);
        if (lane == 0) epart[slot][oh] = ep;
        __syncthreads();
        if (lane == 0 && oh == 0)
            e3[(b * 50 + h) * 20 + w] = tanhf(epart[slot][0] + epart[slot][1] + ab[h * 20 + w]);
    }
    x3p[(size_t)g * 128 + o] = vmax;
}

// ===========================================================================
// Top-k (k=10, value desc, tie -> lower index) + feature recompute.
// z is the t-region only (112000 features per batch row), layout [m][f].
// ev arrays replaced with named registers (no dynamic local indexing).
// ===========================================================================
__global__ __launch_bounds__(64) void k_t1(
    const float* __restrict__ e1, const float* __restrict__ x,
    const float* __restrict__ w1, const float* __restrict__ b1,
    const float* __restrict__ w2, const float* __restrict__ b2,
    float* __restrict__ z)
{
    int blk = blockIdx.x; int b = blk / 50; int h = blk % 50;
    int lane = threadIdx.x;
    const float* er = e1 + (b * 50 + h) * 500;
    float ev0 = er[lane];
    float ev1 = er[64 + lane];
    float ev2 = er[128 + lane];
    float ev3 = er[192 + lane];
    float ev4 = er[256 + lane];
    float ev5 = er[320 + lane];
    float ev6 = er[384 + lane];
    float ev7 = (448 + lane < 500) ? er[448 + lane] : -1e30f;

    for (int k = 0; k < 10; ++k) {
        float bv = ev0; int bi = lane;
        if (ev1 > bv) { bv = ev1; bi = 64 + lane; }
        if (ev2 > bv) { bv = ev2; bi = 128 + lane; }
        if (ev3 > bv) { bv = ev3; bi = 192 + lane; }
        if (ev4 > bv) { bv = ev4; bi = 256 + lane; }
        if (ev5 > bv) { bv = ev5; bi = 320 + lane; }
        if (ev6 > bv) { bv = ev6; bi = 384 + lane; }
        if (ev7 > bv) { bv = ev7; bi = 448 + lane; }
#pragma unroll
        for (int d = 1; d < 64; d <<= 1) {
            float ov = __shfl_xor(bv, d, 64); int oi = __shfl_xor(bi, d, 64);
            if (ov > bv || (ov == bv && oi < bi)) { bv = ov; bi = oi; }
        }
        bool me = (bi & 63) == lane; int cs = bi >> 6;
        if (me && cs == 0) ev0 = -1e30f;
        if (me && cs == 1) ev1 = -1e30f;
        if (me && cs == 2) ev2 = -1e30f;
        if (me && cs == 3) ev3 = -1e30f;
        if (me && cs == 4) ev4 = -1e30f;
        if (me && cs == 5) ev5 = -1e30f;
        if (me && cs == 6) ev6 = -1e30f;
        if (me && cs == 7) ev7 = -1e30f;

        const float* px = x + (size_t)((b * 50 + h) * 500 + bi) * 3;
        float x0 = px[0], x1v = px[1], x2v = px[2];
        int o = lane & 31;
        float v1 = frelu(fmaf(x0, w1[o], fmaf(x1v, w1[32 + o], fmaf(x2v, w1[64 + o], b1[o]))));
        float v2 = b2[o];
#pragma unroll 8
        for (int i = 0; i < 32; ++i) v2 = fmaf(__shfl(v1, i, 64), w2[i * 32 + o], v2);
        if (lane < 32) z[(size_t)b * 112000 + h * 320 + k * 32 + o] = frelu(v2);
    }
}

__global__ __launch_bounds__(64) void k_t2(
    const float* __restrict__ e2, const float* __restrict__ x1p,
    const float* __restrict__ w1, const float* __restrict__ b1,
    const float* __restrict__ w2, const float* __restrict__ b2,
    float* __restrict__ z)
{
    int blk = blockIdx.x; int b = blk / 50; int h = blk % 50;
    int lane = threadIdx.x;
    const float* er = e2 + (b * 50 + h) * 100;
    float ev0 = er[lane] ;
    float ev1 = (64 + lane < 100) ? er[64 + lane] : -1e30f;

    for (int k = 0; k < 10; ++k) {
        float bv = ev0; int bi = lane;
        if (ev1 > bv) { bv = ev1; bi = 64 + lane; }
#pragma unroll
        for (int d = 1; d < 64; d <<= 1) {
            float ov = __shfl_xor(bv, d, 64); int oi = __shfl_xor(bi, d, 64);
            if (ov > bv || (ov == bv && oi < bi)) { bv = ov; bi = oi; }
        }
        bool me = (bi & 63) == lane; int cs = bi >> 6;
        if (me && cs == 0) ev0 = -1e30f;
        if (me && cs == 1) ev1 = -1e30f;

        const float* in = x1p + (size_t)((b * 50 + h) * 100 + bi) * 32;
        float v1 = b1[lane];
#pragma unroll 8
        for (int i = 0; i < 32; ++i) v1 = fmaf(in[i], w1[i * 64 + lane], v1);
        v1 = frelu(v1);
        float v2 = b2[lane];
#pragma unroll 8
        for (int i = 0; i < 64; ++i) v2 = fmaf(__shfl(v1, i, 64), w2[i * 64 + lane], v2);
        z[(size_t)b * 112000 + 16000 + h * 640 + k * 64 + lane] = frelu(v2);
    }
}

__global__ __launch_bounds__(64) void k_t3(
    const float* __restrict__ e3, const float* __restrict__ x2p,
    const float* __restrict__ w1, const float* __restrict__ b1,
    const float* __restrict__ w2, const float* __restrict__ b2,
    float* __restrict__ z)
{
    int blk = blockIdx.x; int b = blk / 50; int h = blk % 50;
    int lane = threadIdx.x;
    const float* er = e3 + (b * 50 + h) * 20;
    float ev0 = (lane < 20) ? er[lane] : -1e30f;

    for (int k = 0; k < 10; ++k) {
        float bv = ev0; int bi = lane;
#pragma unroll
        for (int d = 1; d < 64; d <<= 1) {
            float ov = __shfl_xor(bv, d, 64); int oi = __shfl_xor(bi, d, 64);
            if (ov > bv || (ov == bv && oi < bi)) { bv = ov; bi = oi; }
        }
        if (bi == lane) ev0 = -1e30f;
        const float* in = x2p + (size_t)((b * 50 + h) * 20 + bi) * 64;
        float v1a = b1[lane], v1b = b1[lane + 64];
#pragma unroll 8
        for (int i = 0; i < 64; ++i) {
            float a = in[i];
            v1a = fmaf(a, w1[i * 128 + lane], v1a);
            v1b = fmaf(a, w1[i * 128 + lane + 64], v1b);
        }
        v1a = frelu(v1a); v1b = frelu(v1b);
        float v2a = b2[lane], v2b = b2[lane + 64];
#pragma unroll 8
        for (int i = 0; i < 64; ++i) {
            float s = __shfl(v1a, i, 64);
            v2a = fmaf(s, w2[i * 128 + lane], v2a);
            v2b = fmaf(s, w2[i * 128 + lane + 64], v2b);
        }
#pragma unroll 8
        for (int i = 0; i < 64; ++i) {
            float s = __shfl(v1b, i, 64);
            v2a = fmaf(s, w2[(i + 64) * 128 + lane], v2a);
            v2b = fmaf(s, w2[(i + 64) * 128 + lane + 64], v2b);
        }
        size_t base = (size_t)b * 112000 + 48000 + h * 1280 + k * 128;
        z[base + lane] = frelu(v2a);
        z[base + lane + 64] = frelu(v2b);
    }
}

// ===========================================================================
// k_zt: transpose z[m][f] (f<112000) -> zT[f][m] via 64x64 LDS tiles.
// ===========================================================================
__global__ __launch_bounds__(256) void k_zt(const float* __restrict__ z, float* __restrict__ zT)
{
    __shared__ float t[64][65];
    int f0 = blockIdx.x * 64;                // 1750 blocks
    int tid = threadIdx.x;
    int fl = tid & 63, q = tid >> 6;
#pragma unroll
    for (int rr = 0; rr < 16; ++rr) {
        int m = q * 16 + rr;
        t[m][fl] = z[(size_t)m * 112000 + f0 + fl];
    }
    __syncthreads();
    int m2 = tid & 63;
#pragma unroll
    for (int rr = 0; rr < 16; ++rr) {
        int fl2 = q * 16 + rr;
        zT[(size_t)(f0 + fl2) * 64 + m2] = t[m2][fl2];
    }
}

// ===========================================================================
// k_xf: x3p (B,H,5,128) -> zT rows 112000 + c*250 + h*5 + pw (NCHW flatten),
// transposed to [f][m]. One block per (h,pw).
// ===========================================================================
__global__ __launch_bounds__(256) void k_xf(const float* __restrict__ x3p, float* __restrict__ zT)
{
    __shared__ float t[64][129];
    int blk = blockIdx.x;                    // 250
    int h = blk / 5, pw = blk % 5;
    int tid = threadIdx.x;
    for (int idx = tid; idx < 64 * 128; idx += 256) {
        int m = idx >> 7, c = idx & 127;
        t[m][c] = x3p[(size_t)((m * 50 + h) * 5 + pw) * 128 + c];
    }
    __syncthreads();
    for (int idx = tid; idx < 64 * 128; idx += 256) {
        int c = idx >> 6, m = idx & 63;
        zT[(size_t)(112000 + c * 250 + h * 5 + pw) * 64 + m] = t[m][c];
    }
}

// ===========================================================================
// Skinny GEMM: AT[k][64] (activations transposed, wave-uniform -> s_load),
// W[k][n] coalesced per-lane. Thread = one n column, acc[64] = all m rows.
// part[kc][n][m] partials, reduced by k_red.
// ===========================================================================
__global__ __launch_bounds__(256) void k_gemm(
    const float* __restrict__ AT, const float* __restrict__ W,
    float* __restrict__ part, int K, int N, int KC)
{
    int n = blockIdx.x * 256 + threadIdx.x;
    int kc = blockIdx.y;
    int k0 = kc * KC;
    int k1 = k0 + KC; if (k1 > K) k1 = K;
    float acc[64];
#pragma unroll
    for (int m = 0; m < 64; ++m) acc[m] = 0.f;
#pragma unroll 1
    for (int k = k0; k < k1; ++k) {
        float wv = W[(size_t)k * N + n];
        const float4* Ak4 = (const float4*)(AT + (size_t)k * 64);
#pragma unroll
        for (int mq = 0; mq < 16; ++mq) {
            float4 a = Ak4[mq];
            acc[4 * mq + 0] = fmaf(a.x, wv, acc[4 * mq + 0]);
            acc[4 * mq + 1] = fmaf(a.y, wv, acc[4 * mq + 1]);
            acc[4 * mq + 2] = fmaf(a.z, wv, acc[4 * mq + 2]);
            acc[4 * mq + 3] = fmaf(a.w, wv, acc[4 * mq + 3]);
        }
    }
    float4* p4 = (float4*)(part + ((size_t)kc * N + n) * 64);
#pragma unroll
    for (int mq = 0; mq < 16; ++mq)
        p4[mq] = make_float4(acc[4 * mq], acc[4 * mq + 1], acc[4 * mq + 2], acc[4 * mq + 3]);
}

// Reduce partials; write TRANSPOSED out[n][m] (feeds next layer as AT).
__global__ __launch_bounds__(256) void k_red(
    const float* __restrict__ part, const float* __restrict__ bias,
    float* __restrict__ outT, int N, int C, int doRelu)
{
    int id = blockIdx.x * 256 + threadIdx.x;  // N*64
    int m = id & 63, n = id >> 6;
    float s = 0.f;
    for (int c = 0; c < C; ++c) s += part[((size_t)c * N + n) * 64 + m];
    s += bias[n];
    if (doRelu) s = frelu(s);
    outT[id] = s;                             // outT[n*64 + m]
}

__global__ __launch_bounds__(256) void k_fc3(
    const float* __restrict__ h2T, const float* __restrict__ w3,
    const float* __restrict__ b3, float* __restrict__ out)
{
    int id = blockIdx.x * 256 + threadIdx.x;
    if (id >= 64 * 150) return;
    int m = id / 150, o = id % 150;
    float s = b3[o];
#pragma unroll 4
    for (int k = 0; k < 1024; ++k) s = fmaf(h2T[k * 64 + m], w3[k * 150 + o], s);
    out[id] = s;
}

// ---------------------------------------------------------------------------
extern "C" void kernel_launch(void* const* d_in, const int* in_sizes, int n_in,
                              void* d_out, int out_size, void* d_ws, size_t ws_size,
                              hipStream_t stream) {
    const float* X    = (const float*)d_in[0];
    const float* c1w1 = (const float*)d_in[1];
    const float* c1b1 = (const float*)d_in[2];
    const float* c1w2 = (const float*)d_in[3];
    const float* c1b2 = (const float*)d_in[4];
    const float* a1W  = (const float*)d_in[5];
    const float* a1b  = (const float*)d_in[6];
    const float* c2w1 = (const float*)d_in[7];
    const float* c2b1 = (const float*)d_in[8];
    const float* c2w2 = (const float*)d_in[9];
    const float* c2b2 = (const float*)d_in[10];
    const float* a2W  = (const float*)d_in[11];
    const float* a2b  = (const float*)d_in[12];
    const float* c3w1 = (const float*)d_in[13];
    const float* c3b1 = (const float*)d_in[14];
    const float* c3w2 = (const float*)d_in[15];
    const float* c3b2 = (const float*)d_in[16];
    const float* a3W  = (const float*)d_in[17];
    const float* a3b  = (const float*)d_in[18];
    const float* fc1w = (const float*)d_in[19];
    const float* fc1b = (const float*)d_in[20];
    const float* fc2w = (const float*)d_in[21];
    const float* fc2b = (const float*)d_in[22];
    const float* fc3w = (const float*)d_in[23];
    const float* fc3b = (const float*)d_in[24];

    float* ws  = (float*)d_ws;
    float* x1p = ws;                       // [0, 10.24M)
    float* x2p = ws + 10240000;            // [10.24M, 14.336M)
    float* x3p = ws + 14336000;            // [14.336M, 16.384M)
    float* e1  = ws + 16384000;            // [16.384M, 17.984M)
    float* e2  = ws + 17984000;
    float* e3  = ws + 18304000;
    float* z   = ws + 18368000;            // [18.368M, 25.536M)  7.168M (t-region)
    float* zT  = ws + 25536000;            // [25.536M, 34.752M)  9.216M
    // aliases (safe by ordering): p1 over x1p/x2p; h1T/p2/h2T over x3p/e1
    float* p1  = ws;                       // 200*1024*64 = 13.107M < 14.336M
    float* h1T = ws + 14336000;            // 65536
    float* p2  = ws + 14500000;            // 32*1024*64 = 2.097M (into dead e1)
    float* h2T = ws + 16700000;            // 65536 (dead e1)

    k_s1<<<40000, 256, 0, stream>>>(X, c1w1, c1b1, c1w2, c1b2, a1W, a1b, x1p, e1);
    k_t1<<<3200, 64, 0, stream>>>(e1, X, c1w1, c1b1, c1w2, c1b2, z);
    k_s2<<<16000, 256, 0, stream>>>(x1p, c2w1, c2b1, c2w2, c2b2, a2W, a2b, x2p, e2);
    k_t2<<<3200, 64, 0, stream>>>(e2, x1p, c2w1, c2b1, c2w2, c2b2, z);
    k_s3<<<8000, 256, 0, stream>>>(x2p, c3w1, c3b1, c3w2, c3b2, a3W, a3b, x3p, e3);
    k_t3<<<3200, 64, 0, stream>>>(e3, x2p, c3w1, c3b1, c3w2, c3b2, z);
    k_zt<<<1750, 256, 0, stream>>>(z, zT);
    k_xf<<<250, 256, 0, stream>>>(x3p, zT);

    k_gemm<<<dim3(4, 200), 256, 0, stream>>>(zT, fc1w, p1, 144000, 1024, 720);
    k_red<<<256, 256, 0, stream>>>(p1, fc1b, h1T, 1024, 200, 1);
    k_gemm<<<dim3(4, 32), 256, 0, stream>>>(h1T, fc2w, p2, 1024, 1024, 32);
    k_red<<<256, 256, 0, stream>>>(p2, fc2b, h2T, 1024, 32, 0);
    k_fc3<<<38, 256, 0, stream>>>(h2T, fc3w, fc3b, (float*)d_out);
}

// Round 5
// 1260.993 us; speedup vs baseline: 5.3969x; 1.0450x over previous
//
#include <hip/hip_runtime.h>
#include <math.h>

#define DEV __device__ __forceinline__
DEV float frelu(float x) { return x > 0.f ? x : 0.f; }

typedef float f4 __attribute__((ext_vector_type(4)));

// ===========================================================================
// Stage 1: conv 3->32 relu -> conv 32->32 relu ; e1 = tanh(att) ; pool5 -> x1p
// WREG form: lane = out channel; wave-half = pool group. Each half processes
// NG1=8 groups to amortize the per-lane weight preload.
// ===========================================================================
#define NG1 8
__global__ __launch_bounds__(256) void k_s1(
    const float* __restrict__ x,
    const float* __restrict__ w1, const float* __restrict__ b1,
    const float* __restrict__ w2, const float* __restrict__ b2,
    const float* __restrict__ aW, const float* __restrict__ ab,
    float* __restrict__ x1p, float* __restrict__ e1)
{
    __shared__ float v1s[4][2][32];
    int tid = threadIdx.x;
    int wv = tid >> 6, lane = tid & 63;
    int half = lane >> 5, o = lane & 31;
    int hs = blockIdx.x * 8 + wv * 2 + half;     // 40000 half-slots

    float W1c0 = w1[o], W1c1 = w1[32 + o], W1c2 = w1[64 + o], B1 = b1[o];
    float W2[32];
#pragma unroll
    for (int i = 0; i < 32; ++i) W2[i] = w2[i * 32 + o];
    float B2 = b2[o];
    float* vs = &v1s[wv][half][0];

#pragma unroll 1
    for (int i = 0; i < NG1; ++i) {
        int g = hs * NG1 + i;                    // 0..319999
        int b = g / 5000, r = g % 5000, h = r / 100, pw = r % 100;
        float AWo = aW[h * 32 + o];
        const float* xrow = x + (size_t)((b * 50 + h) * 500) * 3;
        float vmax = 0.f;
#pragma unroll 1
        for (int j = 0; j < 5; ++j) {
            int w = pw * 5 + j;
            float x0 = xrow[w * 3 + 0], x1v = xrow[w * 3 + 1], x2v = xrow[w * 3 + 2];
            float v1 = frelu(fmaf(x0, W1c0, fmaf(x1v, W1c1, fmaf(x2v, W1c2, B1))));
            vs[o] = v1;
            float a2 = B2;
#pragma unroll
            for (int q = 0; q < 32; q += 4) {
                float4 v4 = *(const float4*)&vs[q];
                a2 = fmaf(v4.x, W2[q + 0], a2);
                a2 = fmaf(v4.y, W2[q + 1], a2);
                a2 = fmaf(v4.z, W2[q + 2], a2);
                a2 = fmaf(v4.w, W2[q + 3], a2);
            }
            float t = frelu(a2);
            vmax = fmaxf(vmax, t);
            float ep = t * AWo;
            ep += __shfl_xor(ep, 1, 64);
            ep += __shfl_xor(ep, 2, 64);
            ep += __shfl_xor(ep, 4, 64);
            ep += __shfl_xor(ep, 8, 64);
            ep += __shfl_xor(ep, 16, 64);
            if (o == 0) e1[(b * 50 + h) * 500 + w] = tanhf(ep + ab[h * 500 + w]);
        }
        x1p[(size_t)g * 32 + o] = vmax;
    }
}

// ===========================================================================
// Stage 2: conv 32->64 relu -> conv 64->64 relu ; e2 ; pool5 -> x2p
// WREG: wave = slot, lane = out channel (64); NG2=16 groups per wave.
// ===========================================================================
#define NG2 16
__global__ __launch_bounds__(256) void k_s2(
    const float* __restrict__ x1p,
    const float* __restrict__ w1, const float* __restrict__ b1,
    const float* __restrict__ w2, const float* __restrict__ b2,
    const float* __restrict__ aW, const float* __restrict__ ab,
    float* __restrict__ x2p, float* __restrict__ e2)
{
    __shared__ float v1s[4][64];
    int tid = threadIdx.x;
    int wv = tid >> 6, o = tid & 63;
    int slot = blockIdx.x * 4 + wv;              // 4000 slots

    float W1[32];
#pragma unroll
    for (int i = 0; i < 32; ++i) W1[i] = w1[i * 64 + o];
    float W2[64];
#pragma unroll
    for (int i = 0; i < 64; ++i) W2[i] = w2[i * 64 + o];
    float B1 = b1[o], B2 = b2[o];
    float* vs = &v1s[wv][0];

#pragma unroll 1
    for (int i = 0; i < NG2; ++i) {
        int g = slot * NG2 + i;                  // 0..63999
        int b = g / 1000, r = g % 1000, h = r / 20, pw = r % 20;
        float AWo = aW[h * 64 + o];
        float vmax = 0.f;
#pragma unroll 1
        for (int j = 0; j < 5; ++j) {
            int w = pw * 5 + j;
            const float* in = x1p + (size_t)((b * 50 + h) * 100 + w) * 32;
            float a1 = B1;
#pragma unroll
            for (int q = 0; q < 32; q += 4) {
                float4 a4 = *(const float4*)&in[q];
                a1 = fmaf(a4.x, W1[q + 0], a1);
                a1 = fmaf(a4.y, W1[q + 1], a1);
                a1 = fmaf(a4.z, W1[q + 2], a1);
                a1 = fmaf(a4.w, W1[q + 3], a1);
            }
            vs[o] = frelu(a1);
            float a2 = B2;
#pragma unroll
            for (int q = 0; q < 64; q += 4) {
                float4 v4 = *(const float4*)&vs[q];
                a2 = fmaf(v4.x, W2[q + 0], a2);
                a2 = fmaf(v4.y, W2[q + 1], a2);
                a2 = fmaf(v4.z, W2[q + 2], a2);
                a2 = fmaf(v4.w, W2[q + 3], a2);
            }
            float t = frelu(a2);
            vmax = fmaxf(vmax, t);
            float ep = t * AWo;
            ep += __shfl_xor(ep, 1, 64);
            ep += __shfl_xor(ep, 2, 64);
            ep += __shfl_xor(ep, 4, 64);
            ep += __shfl_xor(ep, 8, 64);
            ep += __shfl_xor(ep, 16, 64);
            ep += __shfl_xor(ep, 32, 64);
            if (o == 0) e2[(b * 50 + h) * 100 + w] = tanhf(ep + ab[h * 100 + w]);
        }
        x2p[(size_t)g * 64 + o] = vmax;
    }
}

// ===========================================================================
// Stage 3: conv 64->128 relu -> conv 128->128 relu ; e3 ; pool4 -> x3p
// Wave-pair covers 128 out channels; NG3=16 groups per slot.
// ===========================================================================
#define NG3 16
__global__ __launch_bounds__(256) void k_s3(
    const float* __restrict__ x2p,
    const float* __restrict__ w1, const float* __restrict__ b1,
    const float* __restrict__ w2, const float* __restrict__ b2,
    const float* __restrict__ aW, const float* __restrict__ ab,
    float* __restrict__ x3p, float* __restrict__ e3)
{
    __shared__ float v1s[2][128];
    __shared__ float epart[2][2];
    int tid = threadIdx.x;
    int wv = tid >> 6, lane = tid & 63;
    int slot = wv >> 1, oh = wv & 1;
    int o = oh * 64 + lane;
    int gs = blockIdx.x * 2 + slot;              // 1000 slots

    float W1[64];
#pragma unroll
    for (int i = 0; i < 64; ++i) W1[i] = w1[i * 128 + o];
    float W2[128];
#pragma unroll
    for (int i = 0; i < 128; ++i) W2[i] = w2[i * 128 + o];
    float B1 = b1[o], B2 = b2[o];

#pragma unroll 1
    for (int i = 0; i < NG3; ++i) {
        int g = gs * NG3 + i;                    // 0..15999
        int b = g / 250, r = g % 250, h = r / 5, pw = r % 5;
        float AWo = aW[h * 128 + o];
        float vmax = 0.f;
#pragma unroll 1
        for (int j = 0; j < 4; ++j) {
            int w = pw * 4 + j;
            const float* in = x2p + (size_t)((b * 50 + h) * 20 + w) * 64;
            float a1 = B1;
#pragma unroll
            for (int q = 0; q < 64; q += 4) {
                float4 a4 = *(const float4*)&in[q];
                a1 = fmaf(a4.x, W1[q + 0], a1);
                a1 = fmaf(a4.y, W1[q + 1], a1);
                a1 = fmaf(a4.z, W1[q + 2], a1);
                a1 = fmaf(a4.w, W1[q + 3], a1);
            }
            v1s[slot][o] = frelu(a1);
            __syncthreads();
            float a2 = B2;
#pragma unroll
            for (int q = 0; q < 128; q += 4) {
                float4 v4 = *(const float4*)&v1s[slot][q];
                a2 = fmaf(v4.x, W2[q + 0], a2);
                a2 = fmaf(v4.y, W2[q + 1], a2);
                a2 = fmaf(v4.z, W2[q + 2], a2);
                a2 = fmaf(v4.w, W2[q + 3], a2);
            }
            float t = frelu(a2);
            vmax = fmaxf(vmax, t);
            float ep = t * AWo;
            ep += __shfl_xor(ep, 1, 64);
            ep += __shfl_xor(ep, 2, 64);
            ep += __shfl_xor(ep, 4, 64);
            ep += __shfl_xor(ep, 8, 64);
            ep += __shfl_xor(ep, 16, 64);
            ep += __shfl_xor(ep, 32, 64);
            if (lane == 0) epart[slot][oh] = ep;
            __syncthreads();
            if (lane == 0 && oh == 0)
                e3[(b * 50 + h) * 20 + w] = tanhf(epart[slot][0] + epart[slot][1] + ab[h * 20 + w]);
        }
        x3p[(size_t)g * 128 + o] = vmax;
    }
}

// ===========================================================================
// Top-k (k=10, value desc, tie -> lower index) + feature recompute.
// ===========================================================================
__global__ __launch_bounds__(64) void k_t1(
    const float* __restrict__ e1, const float* __restrict__ x,
    const float* __restrict__ w1, const float* __restrict__ b1,
    const float* __restrict__ w2, const float* __restrict__ b2,
    float* __restrict__ z)
{
    int blk = blockIdx.x; int b = blk / 50; int h = blk % 50;
    int lane = threadIdx.x;
    const float* er = e1 + (b * 50 + h) * 500;
    float ev0 = er[lane];
    float ev1 = er[64 + lane];
    float ev2 = er[128 + lane];
    float ev3 = er[192 + lane];
    float ev4 = er[256 + lane];
    float ev5 = er[320 + lane];
    float ev6 = er[384 + lane];
    float ev7 = (448 + lane < 500) ? er[448 + lane] : -1e30f;

    for (int k = 0; k < 10; ++k) {
        float bv = ev0; int bi = lane;
        if (ev1 > bv) { bv = ev1; bi = 64 + lane; }
        if (ev2 > bv) { bv = ev2; bi = 128 + lane; }
        if (ev3 > bv) { bv = ev3; bi = 192 + lane; }
        if (ev4 > bv) { bv = ev4; bi = 256 + lane; }
        if (ev5 > bv) { bv = ev5; bi = 320 + lane; }
        if (ev6 > bv) { bv = ev6; bi = 384 + lane; }
        if (ev7 > bv) { bv = ev7; bi = 448 + lane; }
#pragma unroll
        for (int d = 1; d < 64; d <<= 1) {
            float ov = __shfl_xor(bv, d, 64); int oi = __shfl_xor(bi, d, 64);
            if (ov > bv || (ov == bv && oi < bi)) { bv = ov; bi = oi; }
        }
        bool me = (bi & 63) == lane; int cs = bi >> 6;
        if (me && cs == 0) ev0 = -1e30f;
        if (me && cs == 1) ev1 = -1e30f;
        if (me && cs == 2) ev2 = -1e30f;
        if (me && cs == 3) ev3 = -1e30f;
        if (me && cs == 4) ev4 = -1e30f;
        if (me && cs == 5) ev5 = -1e30f;
        if (me && cs == 6) ev6 = -1e30f;
        if (me && cs == 7) ev7 = -1e30f;

        const float* px = x + (size_t)((b * 50 + h) * 500 + bi) * 3;
        float x0 = px[0], x1v = px[1], x2v = px[2];
        int o = lane & 31;
        float v1 = frelu(fmaf(x0, w1[o], fmaf(x1v, w1[32 + o], fmaf(x2v, w1[64 + o], b1[o]))));
        float v2 = b2[o];
#pragma unroll 8
        for (int i = 0; i < 32; ++i) v2 = fmaf(__shfl(v1, i, 64), w2[i * 32 + o], v2);
        if (lane < 32) z[(size_t)b * 112000 + h * 320 + k * 32 + o] = frelu(v2);
    }
}

__global__ __launch_bounds__(64) void k_t2(
    const float* __restrict__ e2, const float* __restrict__ x1p,
    const float* __restrict__ w1, const float* __restrict__ b1,
    const float* __restrict__ w2, const float* __restrict__ b2,
    float* __restrict__ z)
{
    int blk = blockIdx.x; int b = blk / 50; int h = blk % 50;
    int lane = threadIdx.x;
    const float* er = e2 + (b * 50 + h) * 100;
    float ev0 = er[lane];
    float ev1 = (64 + lane < 100) ? er[64 + lane] : -1e30f;

    for (int k = 0; k < 10; ++k) {
        float bv = ev0; int bi = lane;
        if (ev1 > bv) { bv = ev1; bi = 64 + lane; }
#pragma unroll
        for (int d = 1; d < 64; d <<= 1) {
            float ov = __shfl_xor(bv, d, 64); int oi = __shfl_xor(bi, d, 64);
            if (ov > bv || (ov == bv && oi < bi)) { bv = ov; bi = oi; }
        }
        bool me = (bi & 63) == lane; int cs = bi >> 6;
        if (me && cs == 0) ev0 = -1e30f;
        if (me && cs == 1) ev1 = -1e30f;

        const float* in = x1p + (size_t)((b * 50 + h) * 100 + bi) * 32;
        float v1 = b1[lane];
#pragma unroll 8
        for (int i = 0; i < 32; ++i) v1 = fmaf(in[i], w1[i * 64 + lane], v1);
        v1 = frelu(v1);
        float v2 = b2[lane];
#pragma unroll 8
        for (int i = 0; i < 64; ++i) v2 = fmaf(__shfl(v1, i, 64), w2[i * 64 + lane], v2);
        z[(size_t)b * 112000 + 16000 + h * 640 + k * 64 + lane] = frelu(v2);
    }
}

__global__ __launch_bounds__(64) void k_t3(
    const float* __restrict__ e3, const float* __restrict__ x2p,
    const float* __restrict__ w1, const float* __restrict__ b1,
    const float* __restrict__ w2, const float* __restrict__ b2,
    float* __restrict__ z)
{
    int blk = blockIdx.x; int b = blk / 50; int h = blk % 50;
    int lane = threadIdx.x;
    const float* er = e3 + (b * 50 + h) * 20;
    float ev0 = (lane < 20) ? er[lane] : -1e30f;

    for (int k = 0; k < 10; ++k) {
        float bv = ev0; int bi = lane;
#pragma unroll
        for (int d = 1; d < 64; d <<= 1) {
            float ov = __shfl_xor(bv, d, 64); int oi = __shfl_xor(bi, d, 64);
            if (ov > bv || (ov == bv && oi < bi)) { bv = ov; bi = oi; }
        }
        if (bi == lane) ev0 = -1e30f;
        const float* in = x2p + (size_t)((b * 50 + h) * 20 + bi) * 64;
        float v1a = b1[lane], v1b = b1[lane + 64];
#pragma unroll 8
        for (int i = 0; i < 64; ++i) {
            float a = in[i];
            v1a = fmaf(a, w1[i * 128 + lane], v1a);
            v1b = fmaf(a, w1[i * 128 + lane + 64], v1b);
        }
        v1a = frelu(v1a); v1b = frelu(v1b);
        float v2a = b2[lane], v2b = b2[lane + 64];
#pragma unroll 8
        for (int i = 0; i < 64; ++i) {
            float s = __shfl(v1a, i, 64);
            v2a = fmaf(s, w2[i * 128 + lane], v2a);
            v2b = fmaf(s, w2[i * 128 + lane + 64], v2b);
        }
#pragma unroll 8
        for (int i = 0; i < 64; ++i) {
            float s = __shfl(v1b, i, 64);
            v2a = fmaf(s, w2[(i + 64) * 128 + lane], v2a);
            v2b = fmaf(s, w2[(i + 64) * 128 + lane + 64], v2b);
        }
        size_t base = (size_t)b * 112000 + 48000 + h * 1280 + k * 128;
        z[base + lane] = frelu(v2a);
        z[base + lane + 64] = frelu(v2b);
    }
}

// ===========================================================================
// k_zt: transpose z[m][f] (f<112000) -> zT[f][m]
// ===========================================================================
__global__ __launch_bounds__(256) void k_zt(const float* __restrict__ z, float* __restrict__ zT)
{
    __shared__ float t[64][65];
    int f0 = blockIdx.x * 64;                // 1750 blocks
    int tid = threadIdx.x;
    int fl = tid & 63, q = tid >> 6;
#pragma unroll
    for (int rr = 0; rr < 16; ++rr) {
        int m = q * 16 + rr;
        t[m][fl] = z[(size_t)m * 112000 + f0 + fl];
    }
    __syncthreads();
    int m2 = tid & 63;
#pragma unroll
    for (int rr = 0; rr < 16; ++rr) {
        int fl2 = q * 16 + rr;
        zT[(size_t)(f0 + fl2) * 64 + m2] = t[m2][fl2];
    }
}

// ===========================================================================
// k_xf: x3p (B,H,5,128) -> zT rows 112000 + c*250 + h*5 + pw, layout [f][m]
// ===========================================================================
__global__ __launch_bounds__(256) void k_xf(const float* __restrict__ x3p, float* __restrict__ zT)
{
    __shared__ float t[64][129];
    int blk = blockIdx.x;                    // 250
    int h = blk / 5, pw = blk % 5;
    int tid = threadIdx.x;
    for (int idx = tid; idx < 64 * 128; idx += 256) {
        int m = idx >> 7, c = idx & 127;
        t[m][c] = x3p[(size_t)((m * 50 + h) * 5 + pw) * 128 + c];
    }
    __syncthreads();
    for (int idx = tid; idx < 64 * 128; idx += 256) {
        int c = idx >> 6, m = idx & 63;
        zT[(size_t)(112000 + c * 250 + h * 5 + pw) * 64 + m] = t[m][c];
    }
}

// ===========================================================================
// fc1 GEMM: AT[k][64] bf-staged in LDS (double-buffered), W streamed with
// 8-deep prefetch. Thread owns n0=bx*256+tid and n1=n0+512; acc[2][16] f4.
// grid (2, 300), KC=480 (15 LDS chunks of 32 k).
// ===========================================================================
__global__ __launch_bounds__(256) void k_gemm1(
    const float* __restrict__ AT, const float* __restrict__ W,
    float* __restrict__ part)
{
    __shared__ float As[2][32][64];
    int tid = threadIdx.x;
    int n0 = blockIdx.x * 256 + tid;         // [0,512)
    int kc = blockIdx.y;                     // [0,300)
    int k0 = kc * 480;

    f4 acc0[16], acc1[16];
#pragma unroll
    for (int mq = 0; mq < 16; ++mq) { acc0[mq] = (f4)0.f; acc1[mq] = (f4)0.f; }

    // stage chunk 0
    {
        const float4* gsrc = (const float4*)(AT + (size_t)k0 * 64);
        float4 s0 = gsrc[tid], s1 = gsrc[tid + 256];
        float4* l = (float4*)&As[0][0][0];
        l[tid] = s0; l[tid + 256] = s1;
    }
    __syncthreads();

    const float* Wk = W + (size_t)k0 * 1024 + n0;
#pragma unroll 1
    for (int cc = 0; cc < 15; ++cc) {
        int cur = cc & 1;
        float4 s0, s1;
        if (cc < 14) {
            const float4* gsrc = (const float4*)(AT + (size_t)(k0 + (cc + 1) * 32) * 64);
            s0 = gsrc[tid]; s1 = gsrc[tid + 256];     // issue early, consume late
        }
        const float* lbase = &As[cur][0][0];
#pragma unroll 1
        for (int kg = 0; kg < 32; kg += 8) {
            float w0[8], w1[8];
#pragma unroll
            for (int j = 0; j < 8; ++j) {
                size_t off = (size_t)(cc * 32 + kg + j) * 1024;
                w0[j] = Wk[off];
                w1[j] = Wk[off + 512];
            }
#pragma unroll
            for (int j = 0; j < 8; ++j) {
                const f4* ar = (const f4*)(lbase + (kg + j) * 64);
#pragma unroll
                for (int mq = 0; mq < 16; ++mq) {
                    f4 a = ar[mq];
                    acc0[mq] += a * w0[j];
                    acc1[mq] += a * w1[j];
                }
            }
        }
        if (cc < 14) {
            float4* l = (float4*)&As[cur ^ 1][0][0];
            l[tid] = s0; l[tid + 256] = s1;
        }
        __syncthreads();
    }

    f4* p0 = (f4*)(part + ((size_t)kc * 1024 + n0) * 64);
    f4* p1 = (f4*)(part + ((size_t)kc * 1024 + n0 + 512) * 64);
#pragma unroll
    for (int mq = 0; mq < 16; ++mq) { p0[mq] = acc0[mq]; p1[mq] = acc1[mq]; }
}

// ===========================================================================
// Generic skinny GEMM (fc2): AT[k][64] uniform, W[k][n] coalesced.
// ===========================================================================
__global__ __launch_bounds__(256) void k_gemm(
    const float* __restrict__ AT, const float* __restrict__ W,
    float* __restrict__ part, int K, int N, int KC)
{
    int n = blockIdx.x * 256 + threadIdx.x;
    int kc = blockIdx.y;
    int k0 = kc * KC;
    int k1 = k0 + KC; if (k1 > K) k1 = K;
    float acc[64];
#pragma unroll
    for (int m = 0; m < 64; ++m) acc[m] = 0.f;
#pragma unroll 2
    for (int k = k0; k < k1; ++k) {
        float wv = W[(size_t)k * N + n];
        const float4* Ak4 = (const float4*)(AT + (size_t)k * 64);
#pragma unroll
        for (int mq = 0; mq < 16; ++mq) {
            float4 a = Ak4[mq];
            acc[4 * mq + 0] = fmaf(a.x, wv, acc[4 * mq + 0]);
            acc[4 * mq + 1] = fmaf(a.y, wv, acc[4 * mq + 1]);
            acc[4 * mq + 2] = fmaf(a.z, wv, acc[4 * mq + 2]);
            acc[4 * mq + 3] = fmaf(a.w, wv, acc[4 * mq + 3]);
        }
    }
    float4* p4 = (float4*)(part + ((size_t)kc * N + n) * 64);
#pragma unroll
    for (int mq = 0; mq < 16; ++mq)
        p4[mq] = make_float4(acc[4 * mq], acc[4 * mq + 1], acc[4 * mq + 2], acc[4 * mq + 3]);
}

// Reduce partials; write TRANSPOSED out[n][m]. Thread = (n, m-quad), f4 I/O.
__global__ __launch_bounds__(256) void k_red(
    const float* __restrict__ part, const float* __restrict__ bias,
    float* __restrict__ outT, int N, int C, int doRelu)
{
    int id = blockIdx.x * 256 + threadIdx.x;  // N*16
    int mq = id & 15, n = id >> 4;
    f4 s = (f4)0.f;
    for (int c = 0; c < C; ++c)
        s += *(const f4*)(part + ((size_t)c * N + n) * 64 + mq * 4);
    float bv = bias[n];
    s += bv;
    if (doRelu) {
        s.x = frelu(s.x); s.y = frelu(s.y); s.z = frelu(s.z); s.w = frelu(s.w);
    }
    *(f4*)(outT + (size_t)n * 64 + mq * 4) = s;
}

__global__ __launch_bounds__(256) void k_fc3(
    const float* __restrict__ h2T, const float* __restrict__ w3,
    const float* __restrict__ b3, float* __restrict__ out)
{
    int id = blockIdx.x * 256 + threadIdx.x;
    if (id >= 64 * 150) return;
    int m = id / 150, o = id % 150;
    float s = b3[o];
#pragma unroll 4
    for (int k = 0; k < 1024; ++k) s = fmaf(h2T[k * 64 + m], w3[k * 150 + o], s);
    out[id] = s;
}

// ---------------------------------------------------------------------------
extern "C" void kernel_launch(void* const* d_in, const int* in_sizes, int n_in,
                              void* d_out, int out_size, void* d_ws, size_t ws_size,
                              hipStream_t stream) {
    const float* X    = (const float*)d_in[0];
    const float* c1w1 = (const float*)d_in[1];
    const float* c1b1 = (const float*)d_in[2];
    const float* c1w2 = (const float*)d_in[3];
    const float* c1b2 = (const float*)d_in[4];
    const float* a1W  = (const float*)d_in[5];
    const float* a1b  = (const float*)d_in[6];
    const float* c2w1 = (const float*)d_in[7];
    const float* c2b1 = (const float*)d_in[8];
    const float* c2w2 = (const float*)d_in[9];
    const float* c2b2 = (const float*)d_in[10];
    const float* a2W  = (const float*)d_in[11];
    const float* a2b  = (const float*)d_in[12];
    const float* c3w1 = (const float*)d_in[13];
    const float* c3b1 = (const float*)d_in[14];
    const float* c3w2 = (const float*)d_in[15];
    const float* c3b2 = (const float*)d_in[16];
    const float* a3W  = (const float*)d_in[17];
    const float* a3b  = (const float*)d_in[18];
    const float* fc1w = (const float*)d_in[19];
    const float* fc1b = (const float*)d_in[20];
    const float* fc2w = (const float*)d_in[21];
    const float* fc2b = (const float*)d_in[22];
    const float* fc3w = (const float*)d_in[23];
    const float* fc3b = (const float*)d_in[24];

    float* ws  = (float*)d_ws;
    float* x1p = ws;                       // [0, 10.24M)
    float* x2p = ws + 10240000;            // [10.24M, 14.336M)
    float* x3p = ws + 14336000;            // [14.336M, 16.384M)
    float* e1  = ws + 16384000;            // [16.384M, 17.984M)
    float* e2  = ws + 17984000;
    float* e3  = ws + 18304000;
    float* z   = ws + 18368000;            // [18.368M, 25.536M)  (t-region, dead after k_zt)
    float* zT  = ws + 25536000;            // [25.536M, 34.752M)
    // gemm-phase aliases (everything below 25.536M is dead by then):
    float* p1  = ws;                       // 300*1024*64 = 19.66M floats
    float* h1T = ws + 20000000;            // 65536
    float* p2  = ws + 20100000;            // 64*1024*64 = 4.19M
    float* h2T = ws + 24400000;            // 65536 (ends 24.47M < 25.536M)

    k_s1<<<5000, 256, 0, stream>>>(X, c1w1, c1b1, c1w2, c1b2, a1W, a1b, x1p, e1);
    k_t1<<<3200, 64, 0, stream>>>(e1, X, c1w1, c1b1, c1w2, c1b2, z);
    k_s2<<<1000, 256, 0, stream>>>(x1p, c2w1, c2b1, c2w2, c2b2, a2W, a2b, x2p, e2);
    k_t2<<<3200, 64, 0, stream>>>(e2, x1p, c2w1, c2b1, c2w2, c2b2, z);
    k_s3<<<500, 256, 0, stream>>>(x2p, c3w1, c3b1, c3w2, c3b2, a3W, a3b, x3p, e3);
    k_t3<<<3200, 64, 0, stream>>>(e3, x2p, c3w1, c3b1, c3w2, c3b2, z);
    k_zt<<<1750, 256, 0, stream>>>(z, zT);
    k_xf<<<250, 256, 0, stream>>>(x3p, zT);

    k_gemm1<<<dim3(2, 300), 256, 0, stream>>>(zT, fc1w, p1);
    k_red<<<64, 256, 0, stream>>>(p1, fc1b, h1T, 1024, 300, 1);
    k_gemm<<<dim3(4, 64), 256, 0, stream>>>(h1T, fc2w, p2, 1024, 1024, 16);
    k_red<<<64, 256, 0, stream>>>(p2, fc2b, h2T, 1024, 64, 0);
    k_fc3<<<38, 256, 0, stream>>>(h2T, fc3w, fc3b, (float*)d_out);
}